// Round 1
// 482.055 us; speedup vs baseline: 1.0719x; 1.0719x over previous
//
#include <hip/hip_runtime.h>
#include <stdint.h>

// Problem constants (B=2, R=190 -> 380 pairs)
#define PAIRS  380
#define CDIM   512
#define EDIM   256
#define HDIM   8
#define DDIM   32
#define CHUNK  64
#define NCHUNK 8           // CDIM / CHUNK
#define XSTR   260         // ushorts per LDS x-row (+4 pad; 520B stride)
#define NSPLIT 4           // phase-1 blocks per pair
#define CPS    2           // chunks per phase-1 block (NCHUNK/NSPLIT)

// ---- per-pair scratch layout (float offsets) ----
#define Q_OFF      0       // [512][8]   raw q (elu+1)
#define MSH_OFF    4096    // [8][256]   Msh
#define YP_OFF     6144    // [NSPLIT][8][256] y partials
#define QS_OFF     14336   // [NSPLIT][8] Qsum partials
#define KS_OFF     14368   // [NSPLIT][8] Ksum partials
#define SCR_FLOATS 14400
#define OUT_STRIDE 131072  // floats per pair in the output buffer

__device__ __forceinline__ float bf2f(uint16_t u) {
  union { uint32_t i; float f; } v; v.i = ((uint32_t)u) << 16; return v.f;
}
__device__ __forceinline__ uint16_t f2bf(float f) {
  union { float f; uint32_t i; } v; v.f = f;
  return (uint16_t)((v.i + 0x7FFFu + ((v.i >> 16) & 1u)) >> 16);  // RNE
}

// Dtype-generic loads; f32 flag is wave-uniform (runtime). idx%4==0 for ld4.
__device__ __forceinline__ float4 ld4(const void* p, size_t idx, int f32) {
  if (f32) return ((const float4*)p)[idx >> 2];
  ushort4 u = *(const ushort4*)((const uint16_t*)p + idx);
  return make_float4(bf2f(u.x), bf2f(u.y), bf2f(u.z), bf2f(u.w));
}
__device__ __forceinline__ float ld1(const void* p, size_t idx, int f32) {
  return f32 ? ((const float*)p)[idx] : bf2f(((const uint16_t*)p)[idx]);
}

// Per-input dtype sniff. 1 => fp32. All-zero buffers -> bf16 (safe either way).
__global__ void sniff_all(const uint16_t* p0, const uint16_t* p1, const uint16_t* p2,
                          const uint16_t* p3, const uint16_t* p4, const uint16_t* p5,
                          const uint16_t* p6, const uint16_t* p7, const uint16_t* p8,
                          int n0, int n1, int n2, int n3, int n4, int n5, int n6,
                          int n7, int n8, int* __restrict__ flags) {
  const uint16_t* ps[9] = {p0, p1, p2, p3, p4, p5, p6, p7, p8};
  const int       ns[9] = {n0, n1, n2, n3, n4, n5, n6, n7, n8};
  __shared__ int sf;
  const int tid = threadIdx.x;
  #pragma unroll
  for (int j = 0; j < 9; ++j) {
    if (tid == 0) sf = 0;
    __syncthreads();
    const uint16_t* p = ps[j];
    int lim = ns[j] < 4096 ? ns[j] : 4096;
    int huge = 0;
    for (int i = tid; i < lim; i += 256) {
      int e = (p[i] >> 7) & 0xFF;
      huge |= (e >= 0xA0);
    }
    if (huge) atomicOr(&sf, 1);
    __syncthreads();
    if (tid == 0) flags[j] = sf;
    __syncthreads();
  }
}

// ---- Phase 1: per (pair, split) block: stage x chunks -> q/k proj (elu+1)
//      q rows -> scratch; y/Qsum/Ksum partials -> scratch. 1520 blocks.
__global__ void __launch_bounds__(256, 2)
sla_phase1(const void* __restrict__ xg,
           const void* __restrict__ Wq, const void* __restrict__ bq,
           const void* __restrict__ Wk, const void* __restrict__ bk,
           const int* __restrict__ flags,
           float* __restrict__ scratch, long long sstride)
{
  const int fx = flags[0], fwq = flags[1], fbq = flags[2];
  const int fwk = flags[3], fbk = flags[4];

  __shared__ __align__(16) uint16_t xs[CHUNK][XSTR];   // 33280 B
  __shared__ __align__(16) float    wqk[16][EDIM];     // 16384 B
  __shared__ __align__(16) float    kc[CHUNK][HDIM];   //  2048 B

  const int tid  = threadIdx.x;
  const int pair = blockIdx.x / NSPLIT;
  const int sp   = blockIdx.x % NSPLIT;
  const size_t xbase = (size_t)pair * (CDIM * EDIM);
  float* sbase = scratch + (size_t)pair * (size_t)sstride;

  // ---- Wq/Wk rows into LDS as fp32 ----
  for (int i = tid; i < 16 * EDIM / 4; i += 256) {
    int row = i >> 6;                 // 0..15
    int col = (i & 63) << 2;          // 0..252
    float4 w = (row < 8) ? ld4(Wq, (size_t)row * EDIM + col, fwq)
                         : ld4(Wk, (size_t)(row - 8) * EDIM + col, fwk);
    *(float4*)&wqk[row][col] = w;
  }

  const int t  = tid >> 6;            // wave id: {q h0-3, q h4-7, k h0-3, k h4-7}
  const int cl = tid & 63;            // row within chunk
  const int h0 = (t & 1) * 4;
  const void* bsrc = (t < 2) ? bq : bk;
  const int   fb   = (t < 2) ? fbq : fbk;
  const float bias0 = ld1(bsrc, h0 + 0, fb), bias1 = ld1(bsrc, h0 + 1, fb),
              bias2 = ld1(bsrc, h0 + 2, fb), bias3 = ld1(bsrc, h0 + 3, fb);

  float yreg[HDIM] = {0.f,0.f,0.f,0.f,0.f,0.f,0.f,0.f};  // column e = tid
  float cs0 = 0.f, cs1 = 0.f, cs2 = 0.f, cs3 = 0.f;

  for (int ci = 0; ci < CPS; ++ci) {
    const int cbase = (sp * CPS + ci) * CHUNK;
    __syncthreads();                  // xs/kc safe to overwrite (also orders wqk on ci=0)
    // ---- stage 64x256 chunk into LDS as bf16, coalesced ----
    #pragma unroll
    for (int i = 0; i < 16; ++i) {
      int u  = i * 256 + tid;
      int c  = u >> 6;
      int e4 = (u & 63) << 2;
      float4 xv = ld4(xg, xbase + (size_t)(cbase + c) * EDIM + e4, fx);
      ushort4 s; s.x = f2bf(xv.x); s.y = f2bf(xv.y); s.z = f2bf(xv.z); s.w = f2bf(xv.w);
      *(ushort4*)&xs[c][e4] = s;
    }
    __syncthreads();
    // ---- q/k projections: 4 dot-256 for row cl ----
    {
      float a0 = bias0, a1 = bias1, a2 = bias2, a3 = bias3;
      const int r0 = t * 4;
      #pragma unroll 4
      for (int e = 0; e < EDIM; e += 4) {
        ushort4 xv = *(const ushort4*)&xs[cl][e];
        float x0 = bf2f(xv.x), x1 = bf2f(xv.y), x2 = bf2f(xv.z), x3 = bf2f(xv.w);
        float4 w0 = *(const float4*)&wqk[r0 + 0][e];   // wave-uniform broadcast
        float4 w1 = *(const float4*)&wqk[r0 + 1][e];
        float4 w2 = *(const float4*)&wqk[r0 + 2][e];
        float4 w3 = *(const float4*)&wqk[r0 + 3][e];
        a0 += x0 * w0.x + x1 * w0.y + x2 * w0.z + x3 * w0.w;
        a1 += x0 * w1.x + x1 * w1.y + x2 * w1.z + x3 * w1.w;
        a2 += x0 * w2.x + x1 * w2.y + x2 * w2.z + x3 * w2.w;
        a3 += x0 * w3.x + x1 * w3.y + x2 * w3.z + x3 * w3.w;
      }
      a0 = (a0 > 0.f) ? a0 + 1.f : __expf(a0);
      a1 = (a1 > 0.f) ? a1 + 1.f : __expf(a1);
      a2 = (a2 > 0.f) ? a2 + 1.f : __expf(a2);
      a3 = (a3 > 0.f) ? a3 + 1.f : __expf(a3);
      cs0 += a0; cs1 += a1; cs2 += a2; cs3 += a3;
      if (t < 2) *(float4*)&sbase[Q_OFF + (size_t)(cbase + cl) * HDIM + h0]
                   = make_float4(a0, a1, a2, a3);
      else       *(float4*)&kc[cl][h0] = make_float4(a0, a1, a2, a3);
    }
    __syncthreads();
    // ---- y[h, e=tid] += sum_c k[h,c] * x[c,e] ----
    #pragma unroll 8
    for (int c = 0; c < CHUNK; ++c) {
      float xv = bf2f(xs[c][tid]);
      float4 k0 = *(const float4*)&kc[c][0];
      float4 k1 = *(const float4*)&kc[c][4];
      yreg[0] += k0.x * xv; yreg[1] += k0.y * xv; yreg[2] += k0.z * xv; yreg[3] += k0.w * xv;
      yreg[4] += k1.x * xv; yreg[5] += k1.y * xv; yreg[6] += k1.z * xv; yreg[7] += k1.w * xv;
    }
  }

  // ---- Qsum/Ksum wave butterflies (raw partial sums over this block's rows) ----
  #pragma unroll
  for (int off = 32; off >= 1; off >>= 1) {
    cs0 += __shfl_xor(cs0, off, 64);
    cs1 += __shfl_xor(cs1, off, 64);
    cs2 += __shfl_xor(cs2, off, 64);
    cs3 += __shfl_xor(cs3, off, 64);
  }
  if ((tid & 63) == 0) {
    if (t < 2) *(float4*)&sbase[QS_OFF + sp * HDIM + h0] = make_float4(cs0, cs1, cs2, cs3);
    else       *(float4*)&sbase[KS_OFF + sp * HDIM + h0] = make_float4(cs0, cs1, cs2, cs3);
  }

  // ---- y partials ----
  float* yp = sbase + YP_OFF + (size_t)sp * (HDIM * EDIM);
  #pragma unroll
  for (int h = 0; h < HDIM; ++h) yp[h * EDIM + tid] = yreg[h];
}

// ---- Phase 2: per pair: reduce partials -> ktv -> Msh. 380 blocks. ----
__global__ void __launch_bounds__(256, 2)
sla_phase2(const void* __restrict__ Wv, const void* __restrict__ bv,
           const void* __restrict__ Wo,
           const int* __restrict__ flags,
           float* __restrict__ scratch, long long sstride)
{
  const int fwv = flags[5], fbv = flags[6], fwo = flags[7];
  __shared__ __align__(16) float ysh[HDIM][EDIM];   // y / Ksum
  __shared__ __align__(16) float ktv[HDIM][DDIM];
  __shared__ float sQ[HDIM], sK[HDIM];
  const int tid = threadIdx.x;
  float* sbase = scratch + (size_t)blockIdx.x * (size_t)sstride;

  if (tid < 16) {
    int h = tid & 7;
    const float* ps = sbase + ((tid < 8) ? QS_OFF : KS_OFF);
    float s = 0.f;
    #pragma unroll
    for (int sp = 0; sp < NSPLIT; ++sp) s += ps[sp * HDIM + h];
    if (tid < 8) sQ[h] = 512.f / s;
    else         sK[h] = 1.f / s;
  }
  __syncthreads();

  {
    const float* yp = sbase + YP_OFF;
    #pragma unroll
    for (int h = 0; h < HDIM; ++h) {
      float y = 0.f;
      #pragma unroll
      for (int sp = 0; sp < NSPLIT; ++sp) y += yp[(sp * HDIM + h) * EDIM + tid];
      ysh[h][tid] = y * sK[h];
    }
  }
  __syncthreads();

  // ---- ktv[h,d] = ysh[h,:] . Wv[h*32+d,:] + bv ----
  {
    const int h = tid >> 5, d = tid & 31;
    const size_t wvrow = (size_t)(h * DDIM + d) * EDIM;
    float acc = 0.f;
    #pragma unroll 4
    for (int e = 0; e < EDIM; e += 8) {
      float4 wa = ld4(Wv, wvrow + e, fwv);
      float4 wb = ld4(Wv, wvrow + e + 4, fwv);
      float4 ya = *(const float4*)&ysh[h][e];
      float4 yb = *(const float4*)&ysh[h][e + 4];
      acc += wa.x * ya.x + wa.y * ya.y + wa.z * ya.z + wa.w * ya.w
           + wb.x * yb.x + wb.y * yb.y + wb.z * yb.z + wb.w * yb.w;
    }
    ktv[h][d] = acc + ld1(bv, h * DDIM + d, fbv);
  }
  __syncthreads();

  // ---- Msh[h][f] = (C/Qsum[h]) * ktv[h,:] . Wo[f, h*32..] ----
  {
    const int f = tid;
    const size_t worow = (size_t)f * EDIM;
    float* msh = sbase + MSH_OFF;
    #pragma unroll
    for (int h = 0; h < HDIM; ++h) {
      float m = 0.f;
      #pragma unroll
      for (int d = 0; d < DDIM; d += 8) {
        float4 wa = ld4(Wo, worow + h * DDIM + d, fwo);
        float4 wb = ld4(Wo, worow + h * DDIM + d + 4, fwo);
        float4 ka = *(const float4*)&ktv[h][d];
        float4 kb = *(const float4*)&ktv[h][d + 4];
        m += wa.x * ka.x + wa.y * ka.y + wa.z * ka.z + wa.w * ka.w
           + wb.x * kb.x + wb.y * kb.y + wb.z * kb.z + wb.w * kb.w;
      }
      msh[h * EDIM + f] = m * sQ[h];
    }
  }
}

// ---- Phase 3: rank-8 epilogue, streaming fp32 output.
//      shift=2: 4 blocks/pair (scratch in ws). shift=0: 1 block/pair
//      (scratch aliased into out region; stage to LDS, sync, then overwrite).
__global__ void __launch_bounds__(256, 2)
sla_phase3(const float* __restrict__ scratch, long long sstride,
           const void* __restrict__ bo, const int* __restrict__ flags,
           float* __restrict__ outg, int shift)
{
  const int fbo = flags[8];
  __shared__ __align__(16) float qsh[CDIM][HDIM];   // 16 KB (worst case)
  __shared__ __align__(16) float msh[HDIM][EDIM];   //  8 KB
  const int tid  = threadIdx.x;
  const int pair = blockIdx.x >> shift;
  const int seg  = blockIdx.x & ((1 << shift) - 1);
  const int rows = CDIM >> shift;
  const int c0   = seg * rows;
  const float* sbase = scratch + (size_t)pair * (size_t)sstride;

  // stage q rows [c0, c0+rows) and Msh into LDS
  for (int i = tid; i < rows * HDIM / 4; i += 256) {
    *(float4*)&qsh[i >> 1][(i & 1) * 4] =
        *(const float4*)&sbase[Q_OFF + (size_t)c0 * HDIM + (size_t)i * 4];
  }
  {
    const float* mp = sbase + MSH_OFF;
    for (int i = tid; i < HDIM * EDIM / 4; i += 256) {
      *(float4*)((float*)msh + (size_t)i * 4) = *(const float4*)&mp[(size_t)i * 4];
    }
  }
  __syncthreads();

  const int fq = tid & 63, cg = tid >> 6;
  const int f0 = fq * 4;
  float M[HDIM][4];
  #pragma unroll
  for (int h = 0; h < HDIM; ++h) {
    float4 mm = *(const float4*)&msh[h][f0];
    M[h][0] = mm.x; M[h][1] = mm.y; M[h][2] = mm.z; M[h][3] = mm.w;
  }
  const float b0 = ld1(bo, f0 + 0, fbo), b1 = ld1(bo, f0 + 1, fbo),
              b2 = ld1(bo, f0 + 2, fbo), b3 = ld1(bo, f0 + 3, fbo);
  float* outp = outg + (size_t)pair * OUT_STRIDE;
  const int rpw = rows >> 2;   // rows per wave
  for (int i = 0; i < rpw; ++i) {
    int c = cg * rpw + i;      // local row in qsh; global row = c0 + c
    float4 qa = *(const float4*)&qsh[c][0];   // wave-uniform broadcast
    float4 qb = *(const float4*)&qsh[c][4];
    float o0 = b0 + qa.x * M[0][0] + qa.y * M[1][0] + qa.z * M[2][0] + qa.w * M[3][0]
                  + qb.x * M[4][0] + qb.y * M[5][0] + qb.z * M[6][0] + qb.w * M[7][0];
    float o1 = b1 + qa.x * M[0][1] + qa.y * M[1][1] + qa.z * M[2][1] + qa.w * M[3][1]
                  + qb.x * M[4][1] + qb.y * M[5][1] + qb.z * M[6][1] + qb.w * M[7][1];
    float o2 = b2 + qa.x * M[0][2] + qa.y * M[1][2] + qa.z * M[2][2] + qa.w * M[3][2]
                  + qb.x * M[4][2] + qb.y * M[5][2] + qb.z * M[6][2] + qb.w * M[7][2];
    float o3 = b3 + qa.x * M[0][3] + qa.y * M[1][3] + qa.z * M[2][3] + qa.w * M[3][3]
                  + qb.x * M[4][3] + qb.y * M[5][3] + qb.z * M[6][3] + qb.w * M[7][3];
    *(float4*)(outp + (size_t)(c0 + c) * EDIM + f0) = make_float4(o0, o1, o2, o3);
  }
}

extern "C" void kernel_launch(void* const* d_in, const int* in_sizes, int n_in,
                              void* d_out, int out_size, void* d_ws, size_t ws_size,
                              hipStream_t stream) {
  (void)n_in; (void)out_size;
  int* flags = (int*)d_ws;
  hipLaunchKernelGGL(sniff_all, dim3(1), dim3(256), 0, stream,
                     (const uint16_t*)d_in[0], (const uint16_t*)d_in[1],
                     (const uint16_t*)d_in[2], (const uint16_t*)d_in[3],
                     (const uint16_t*)d_in[4], (const uint16_t*)d_in[5],
                     (const uint16_t*)d_in[6], (const uint16_t*)d_in[7],
                     (const uint16_t*)d_in[8],
                     in_sizes[0], in_sizes[1], in_sizes[2], in_sizes[3], in_sizes[4],
                     in_sizes[5], in_sizes[6], in_sizes[7], in_sizes[8], flags);

  // Scratch placement: workspace if big enough, else stash inside each pair's
  // own output region (phase3 then runs 1 block/pair, staging before overwrite).
  const size_t need = 256 + (size_t)PAIRS * SCR_FLOATS * sizeof(float);
  float*    scratch;
  long long sstride;
  int       shift;
  if (ws_size >= need) {
    scratch = (float*)((char*)d_ws + 256);
    sstride = SCR_FLOATS;
    shift   = 2;            // 4 epilogue blocks per pair
  } else {
    scratch = (float*)d_out;
    sstride = OUT_STRIDE;
    shift   = 0;            // 1 epilogue block per pair (stage-then-overwrite)
  }

  hipLaunchKernelGGL(sla_phase1, dim3(PAIRS * NSPLIT), dim3(256), 0, stream,
                     d_in[0], d_in[1], d_in[2], d_in[3], d_in[4],
                     (const int*)flags, scratch, sstride);
  hipLaunchKernelGGL(sla_phase2, dim3(PAIRS), dim3(256), 0, stream,
                     d_in[5], d_in[6], d_in[7], (const int*)flags, scratch, sstride);
  hipLaunchKernelGGL(sla_phase3, dim3(PAIRS << shift), dim3(256), 0, stream,
                     scratch, sstride, d_in[8], (const int*)flags,
                     (float*)d_out, shift);
}